// Round 1
// baseline (1053.072 us; speedup 1.0000x reference)
//
#include <hip/hip_runtime.h>
#include <cstdint>
#include <cstddef>

// Problem constants (from reference setup)
#define SEQ   2048
#define HID   1024
#define NBAT  64
#define NSEG  4
#define NNODE 7
#define TCHUNK 256   // tokens per pooling block chunk (SEQ/TCHUNK = 8 chunks)

__device__ __forceinline__ float gelu_f(float x) {
  // exact erf gelu (jax approximate=False / torch default GELU)
  return 0.5f * x * (1.0f + erff(x * 0.7071067811865476f));
}

// ---------------------------------------------------------------------------
// Kernel 1: ragged segment-sum pooling.
// Segment s of batch b is the contiguous token interval [bnd[s], bnd[s+1]),
// bnd[4] := len  (seg_id = count(boundaries <= t) - 1; duplicates => empty seg).
// Grid: (SEQ/TCHUNK, B). Block: 256 threads, thread t owns h = 4*t..4*t+3.
// Partial sums atomically added into pooled_sum[b][s][h] (zeroed beforehand).
// ---------------------------------------------------------------------------
__global__ __launch_bounds__(256) void pool_kernel(
    const float* __restrict__ states, const int* __restrict__ boundaries,
    const int* __restrict__ lengths, float* __restrict__ pooled_sum)
{
  const int tc = blockIdx.x, b = blockIdx.y;
  const int tid = threadIdx.x;
  const int len = lengths[b];
  int bnd[5];
  bnd[0] = boundaries[b * 4 + 0];
  bnd[1] = boundaries[b * 4 + 1];
  bnd[2] = boundaries[b * 4 + 2];
  bnd[3] = boundaries[b * 4 + 3];
  bnd[4] = len;
  const int clo = tc * TCHUNK, chi = clo + TCHUNK;
  const float4* S = (const float4*)(states + (size_t)b * SEQ * HID);

  #pragma unroll
  for (int s = 0; s < NSEG; ++s) {
    int lo = bnd[s]     > clo ? bnd[s]     : clo;
    int hi = bnd[s + 1] < chi ? bnd[s + 1] : chi;
    if (lo >= hi) continue;                       // block-uniform branch
    float4 acc = make_float4(0.f, 0.f, 0.f, 0.f);
    int t = lo;
    for (; t + 4 <= hi; t += 4) {
      float4 v0 = S[(size_t)(t + 0) * (HID / 4) + tid];
      float4 v1 = S[(size_t)(t + 1) * (HID / 4) + tid];
      float4 v2 = S[(size_t)(t + 2) * (HID / 4) + tid];
      float4 v3 = S[(size_t)(t + 3) * (HID / 4) + tid];
      acc.x += (v0.x + v1.x) + (v2.x + v3.x);
      acc.y += (v0.y + v1.y) + (v2.y + v3.y);
      acc.z += (v0.z + v1.z) + (v2.z + v3.z);
      acc.w += (v0.w + v1.w) + (v2.w + v3.w);
    }
    for (; t < hi; ++t) {
      float4 v = S[(size_t)t * (HID / 4) + tid];
      acc.x += v.x; acc.y += v.y; acc.z += v.z; acc.w += v.w;
    }
    float* dst = pooled_sum + (size_t)(b * NSEG + s) * HID + tid * 4;
    atomicAdd(dst + 0, acc.x);
    atomicAdd(dst + 1, acc.y);
    atomicAdd(dst + 2, acc.z);
    atomicAdd(dst + 3, acc.w);
  }
}

// ---------------------------------------------------------------------------
// Generic fp32 tiled GEMM: C[M x 1024] = epi(A[M x K] @ W[K x 1024] + bias)
// Tile 32(M) x 64(N) x 32(K), 256 threads, 2x4 accumulators/thread.
// AMODE: 0 = plain A, 1 = pooled_sum (scale rows by 1/max(cnt,1)),
//        2 = gather concat(node_repr[lc], node_repr[rc]) rows.
// EPI:   0 = gelu -> C
//        1 = leaf scatter: (x + b + dembed[depth[leaf]]) * leaf_ok -> node_repr
//        2 = merge scatter: (x + b + dembed[depth[node]]) * is_int -> node_repr
// ---------------------------------------------------------------------------
#define BM 32
#define BN 64
#define BK 32

template<int AMODE, int EPI>
__global__ __launch_bounds__(256) void gemm_kernel(
    const float* __restrict__ A, const float* __restrict__ W,
    const float* __restrict__ bias, float* __restrict__ C,
    int M, int K,
    const int* __restrict__ boundaries, const int* __restrict__ lengths,
    const int* __restrict__ leaf_order, const int* __restrict__ active,
    const int* __restrict__ is_leaf, const int* __restrict__ depth,
    const int* __restrict__ left_child, const int* __restrict__ right_child,
    const float* __restrict__ dembed,
    const float* __restrict__ node_in, float* __restrict__ node_out,
    int nodeA, int nodeB)
{
  const int N = 1024;
  __shared__ float As[BK][BM + 2];   // padded, stride 34 (even -> aligned float2)
  __shared__ float Ws[BK][BN];
  __shared__ float sInv[BM];

  const int tid = threadIdx.x;
  const int n0 = blockIdx.x * BN;
  const int m0 = blockIdx.y * BM;

  if (AMODE == 1) {
    if (tid < BM) {
      int m = m0 + tid; int b = m >> 2; int s = m & 3;
      int bs = boundaries[b * 4 + s];
      int bn = (s < 3) ? boundaries[b * 4 + s + 1] : lengths[b];
      sInv[tid] = 1.0f / fmaxf((float)(bn - bs), 1.0f);
    }
  }

  float acc[2][4] = {{0.f,0.f,0.f,0.f},{0.f,0.f,0.f,0.f}};
  const int am = tid >> 3;            // 0..31   A tile row
  const int ak = (tid & 7) * 4;       // 0..28   A tile k
  const int wk = tid >> 3;            // 0..31   W tile k
  const int wn = (tid & 7) * 8;       // 0..56   W tile n
  const int rm = (tid >> 4) * 2;      // compute rows
  const int cn = (tid & 15) * 4;      // compute cols

  for (int k0 = 0; k0 < K; k0 += BK) {
    float4 av;
    if (AMODE == 2) {
      int mrow = m0 + am; int mi = mrow >> 6; int b = mrow & 63;
      int node = mi ? nodeB : nodeA;
      int col = k0 + ak;
      int child = (col < 1024) ? left_child[node] : right_child[node];
      int c2    = (col < 1024) ? col : col - 1024;
      av = *(const float4*)(node_in + (size_t)(b * NNODE + child) * 1024 + c2);
    } else {
      av = *(const float4*)(A + (size_t)(m0 + am) * K + k0 + ak);
    }
    float4 wv0 = *(const float4*)(W + (size_t)(k0 + wk) * N + n0 + wn);
    float4 wv1 = *(const float4*)(W + (size_t)(k0 + wk) * N + n0 + wn + 4);

    __syncthreads();   // previous tile consumed (also covers sInv on iter 0)
    if (AMODE == 1) {
      float iv = sInv[am];
      av.x *= iv; av.y *= iv; av.z *= iv; av.w *= iv;
    }
    As[ak + 0][am] = av.x;
    As[ak + 1][am] = av.y;
    As[ak + 2][am] = av.z;
    As[ak + 3][am] = av.w;
    *(float4*)&Ws[wk][wn]     = wv0;
    *(float4*)&Ws[wk][wn + 4] = wv1;
    __syncthreads();

    #pragma unroll
    for (int kk = 0; kk < BK; ++kk) {
      float2 a2 = *(const float2*)&As[kk][rm];
      float4 w  = *(const float4*)&Ws[kk][cn];
      acc[0][0] += a2.x * w.x; acc[0][1] += a2.x * w.y;
      acc[0][2] += a2.x * w.z; acc[0][3] += a2.x * w.w;
      acc[1][0] += a2.y * w.x; acc[1][1] += a2.y * w.y;
      acc[1][2] += a2.y * w.z; acc[1][3] += a2.y * w.w;
    }
  }

  // ---- epilogue ----
  #pragma unroll
  for (int r = 0; r < 2; ++r) {
    const int m = m0 + rm + r;
    const int n = n0 + cn;
    float4 x;
    x.x = acc[r][0] + bias[n + 0];
    x.y = acc[r][1] + bias[n + 1];
    x.z = acc[r][2] + bias[n + 2];
    x.w = acc[r][3] + bias[n + 3];

    if (EPI == 0) {
      x.x = gelu_f(x.x); x.y = gelu_f(x.y); x.z = gelu_f(x.z); x.w = gelu_f(x.w);
      *(float4*)(C + (size_t)m * N + n) = x;
    } else if (EPI == 1) {
      int b = m >> 2; int s = m & 3;
      int node  = leaf_order[b * 4 + s];
      int nclip = node < 0 ? 0 : node;
      int bs = boundaries[b * 4 + s];
      int bn = (s < 3) ? boundaries[b * 4 + s + 1] : lengths[b];
      bool ok = (node >= 0) && (is_leaf[b * NNODE + nclip] != 0) && (bn - bs > 0);
      int d = depth[nclip];
      const float* de = dembed + (size_t)d * 1024 + n;
      float sc = ok ? 1.0f : 0.0f;
      x.x = (x.x + de[0]) * sc; x.y = (x.y + de[1]) * sc;
      x.z = (x.z + de[2]) * sc; x.w = (x.w + de[3]) * sc;
      *(float4*)(node_out + (size_t)(b * NNODE + nclip) * 1024 + n) = x;
    } else { // EPI == 2
      int mi = m >> 6; int b = m & 63;
      int node = mi ? nodeB : nodeA;
      bool ii = (active[b * NNODE + node] != 0) && (is_leaf[b * NNODE + node] == 0);
      int d = depth[node];
      const float* de = dembed + (size_t)d * 1024 + n;
      float sc = ii ? 1.0f : 0.0f;
      x.x = (x.x + de[0]) * sc; x.y = (x.y + de[1]) * sc;
      x.z = (x.z + de[2]) * sc; x.w = (x.w + de[3]) * sc;
      *(float4*)(node_out + (size_t)(b * NNODE + node) * 1024 + n) = x;
    }
  }
}

// ---------------------------------------------------------------------------
// Final: out[b] = node_repr[b][0] + shape_embed[abs(hash(b)) % 256]
// ---------------------------------------------------------------------------
__global__ __launch_bounds__(256) void final_kernel(
    const float* __restrict__ node_repr, const float* __restrict__ shape_embed,
    const int* __restrict__ active, const int* __restrict__ is_leaf,
    float* __restrict__ out)
{
  const int b = blockIdx.x;
  const int tid = threadIdx.x;
  long long h = 0, w = 1;
  #pragma unroll
  for (int i = 0; i < NNODE; ++i) {
    long long p = (long long)active[b * NNODE + i] * 2 + (long long)is_leaf[b * NNODE + i];
    h += p * w;
    w *= 31;
  }
  long long a = h < 0 ? -h : h;
  int sid = (int)(a % 256);
  float4 v = *(const float4*)(node_repr + (size_t)(b * NNODE) * 1024 + tid * 4);
  float4 e = *(const float4*)(shape_embed + (size_t)sid * 1024 + tid * 4);
  v.x += e.x; v.y += e.y; v.z += e.z; v.w += e.w;
  *(float4*)(out + (size_t)b * 1024 + tid * 4) = v;
}

// ---------------------------------------------------------------------------
extern "C" void kernel_launch(void* const* d_in, const int* in_sizes, int n_in,
                              void* d_out, int out_size, void* d_ws, size_t ws_size,
                              hipStream_t stream)
{
  const float* states     = (const float*)d_in[0];
  // d_in[1] (mask) is redundant: mask[b][t] == (t < lengths[b])
  const int* lengths      = (const int*)d_in[2];
  const int* boundaries   = (const int*)d_in[3];
  const int* leaf_order   = (const int*)d_in[4];
  const int* active       = (const int*)d_in[5];
  const int* is_leaf      = (const int*)d_in[6];
  const int* left_child   = (const int*)d_in[7];
  const int* right_child  = (const int*)d_in[8];
  const int* depth        = (const int*)d_in[9];
  const float* W1  = (const float*)d_in[10];
  const float* b1  = (const float*)d_in[11];
  const float* W2  = (const float*)d_in[12];
  const float* b2  = (const float*)d_in[13];
  const float* Wm1 = (const float*)d_in[14];
  const float* bm1 = (const float*)d_in[15];
  const float* Wm2 = (const float*)d_in[16];
  const float* bm2 = (const float*)d_in[17];
  const float* dembed = (const float*)d_in[18];
  const float* sembed = (const float*)d_in[19];
  float* out = (float*)d_out;

  // workspace layout (floats)
  float* pooled    = (float*)d_ws;              // 256*1024 (zero-init)
  float* H1        = pooled + 256 * 1024;       // 256*1024
  float* Hm        = H1 + 256 * 1024;           // 128*1024
  float* node_repr = Hm + 128 * 1024;           // 448*1024
  // total 1088 KiB * 4 = ~4.25 MB

  hipMemsetAsync(pooled, 0, (size_t)256 * 1024 * sizeof(float), stream);

  // 1) pooling partial sums
  pool_kernel<<<dim3(SEQ / TCHUNK, NBAT), 256, 0, stream>>>(
      states, boundaries, lengths, pooled);

  // 2) H1 = gelu(pooled/cnt @ W1 + b1)            M=256 K=1024
  gemm_kernel<1, 0><<<dim3(16, 8), 256, 0, stream>>>(
      pooled, W1, b1, H1, 256, 1024,
      boundaries, lengths, leaf_order, active, is_leaf, depth,
      left_child, right_child, dembed, nullptr, nullptr, -1, -1);

  // 3) leaves: node_repr[leaf] = (H1 @ W2 + b2 + dembed) * leaf_ok   M=256 K=1024
  gemm_kernel<0, 1><<<dim3(16, 8), 256, 0, stream>>>(
      H1, W2, b2, nullptr, 256, 1024,
      boundaries, lengths, leaf_order, active, is_leaf, depth,
      left_child, right_child, dembed, nullptr, node_repr, -1, -1);

  // 4) level-1 merges (nodes 1 and 2, independent):  M=128 K=2048
  gemm_kernel<2, 0><<<dim3(16, 4), 256, 0, stream>>>(
      nullptr, Wm1, bm1, Hm, 128, 2048,
      boundaries, lengths, leaf_order, active, is_leaf, depth,
      left_child, right_child, dembed, node_repr, nullptr, 1, 2);
  gemm_kernel<0, 2><<<dim3(16, 4), 256, 0, stream>>>(
      Hm, Wm2, bm2, nullptr, 128, 1024,
      boundaries, lengths, leaf_order, active, is_leaf, depth,
      left_child, right_child, dembed, nullptr, node_repr, 1, 2);

  // 5) root merge (node 0):  M=64 K=2048
  gemm_kernel<2, 0><<<dim3(16, 2), 256, 0, stream>>>(
      nullptr, Wm1, bm1, Hm, 64, 2048,
      boundaries, lengths, leaf_order, active, is_leaf, depth,
      left_child, right_child, dembed, node_repr, nullptr, 0, 0);
  gemm_kernel<0, 2><<<dim3(16, 2), 256, 0, stream>>>(
      Hm, Wm2, bm2, nullptr, 64, 1024,
      boundaries, lengths, leaf_order, active, is_leaf, depth,
      left_child, right_child, dembed, nullptr, node_repr, 0, 0);

  // 6) out = node_repr[:,0] + shape_embed[hash]
  final_kernel<<<dim3(NBAT), 256, 0, stream>>>(
      node_repr, sembed, active, is_leaf, out);
}

// Round 2
// 963.280 us; speedup vs baseline: 1.0932x; 1.0932x over previous
//
#include <hip/hip_runtime.h>
#include <cstdint>
#include <cstddef>

// Problem constants (from reference setup)
#define SEQ   2048
#define HID   1024
#define NBAT  64
#define NSEG  4
#define NNODE 7
#define TCHUNK 128   // tokens per pooling block chunk (SEQ/TCHUNK = 16 chunks)

__device__ __forceinline__ float gelu_f(float x) {
  // exact erf gelu (jax approximate=False / torch default GELU)
  return 0.5f * x * (1.0f + erff(x * 0.7071067811865476f));
}

// ---------------------------------------------------------------------------
// Kernel 1: ragged segment-sum pooling.
// Segment s of batch b is the contiguous token interval [bnd[s], bnd[s+1]),
// bnd[4] := len. Grid: (SEQ/TCHUNK, B). Block: 256 threads, thread owns
// h = 4*tid..4*tid+3. Partial sums atomically added into pooled_sum (zeroed).
// ---------------------------------------------------------------------------
__global__ __launch_bounds__(256) void pool_kernel(
    const float* __restrict__ states, const int* __restrict__ boundaries,
    const int* __restrict__ lengths, float* __restrict__ pooled_sum)
{
  const int tc = blockIdx.x, b = blockIdx.y;
  const int tid = threadIdx.x;
  const int len = lengths[b];
  int bnd[5];
  bnd[0] = boundaries[b * 4 + 0];
  bnd[1] = boundaries[b * 4 + 1];
  bnd[2] = boundaries[b * 4 + 2];
  bnd[3] = boundaries[b * 4 + 3];
  bnd[4] = len;
  const int clo = tc * TCHUNK, chi = clo + TCHUNK;
  const float4* S = (const float4*)(states + (size_t)b * SEQ * HID);

  #pragma unroll
  for (int s = 0; s < NSEG; ++s) {
    int lo = bnd[s]     > clo ? bnd[s]     : clo;
    int hi = bnd[s + 1] < chi ? bnd[s + 1] : chi;
    if (lo >= hi) continue;                       // block-uniform branch
    float4 acc = make_float4(0.f, 0.f, 0.f, 0.f);
    int t = lo;
    for (; t + 4 <= hi; t += 4) {
      float4 v0 = S[(size_t)(t + 0) * (HID / 4) + tid];
      float4 v1 = S[(size_t)(t + 1) * (HID / 4) + tid];
      float4 v2 = S[(size_t)(t + 2) * (HID / 4) + tid];
      float4 v3 = S[(size_t)(t + 3) * (HID / 4) + tid];
      acc.x += (v0.x + v1.x) + (v2.x + v3.x);
      acc.y += (v0.y + v1.y) + (v2.y + v3.y);
      acc.z += (v0.z + v1.z) + (v2.z + v3.z);
      acc.w += (v0.w + v1.w) + (v2.w + v3.w);
    }
    for (; t < hi; ++t) {
      float4 v = S[(size_t)t * (HID / 4) + tid];
      acc.x += v.x; acc.y += v.y; acc.z += v.z; acc.w += v.w;
    }
    float* dst = pooled_sum + (size_t)(b * NSEG + s) * HID + tid * 4;
    atomicAdd(dst + 0, acc.x);
    atomicAdd(dst + 1, acc.y);
    atomicAdd(dst + 2, acc.z);
    atomicAdd(dst + 3, acc.w);
  }
}

// ---------------------------------------------------------------------------
// Generic fp32 tiled GEMM: C[M x 1024] = epi(A[M x K] @ W[K x 1024] + bias)
// Tile 32(M) x 64(N) x 32(K), 256 threads, 2x4 accumulators/thread.
// Register-prefetch pipeline: next tile's global loads are issued right
// after the staging barrier, before the compute block -> vmcnt wait lands at
// the NEXT iteration's LDS store (latency hidden even at 1 wave/SIMD).
// AMODE: 0 = plain A, 1 = pooled_sum (scale rows by 1/max(cnt,1)),
//        2 = gather concat(node_repr[lc], node_repr[rc]) rows.
// EPI:   0 = gelu -> C
//        1 = leaf scatter: (x + b + dembed[depth[leaf]]) * leaf_ok -> node_repr
//        2 = merge scatter: (x + b + dembed[depth[node]]) * is_int -> node_repr
//        3 = root merge + topology hash + shape_embed add -> d_out
// ---------------------------------------------------------------------------
#define BM 32
#define BN 64
#define BK 32

template<int AMODE, int EPI>
__global__ __launch_bounds__(256) void gemm_kernel(
    const float* __restrict__ A, const float* __restrict__ W,
    const float* __restrict__ bias, float* __restrict__ C,
    int M, int K,
    const int* __restrict__ boundaries, const int* __restrict__ lengths,
    const int* __restrict__ leaf_order, const int* __restrict__ active,
    const int* __restrict__ is_leaf, const int* __restrict__ depth,
    const int* __restrict__ left_child, const int* __restrict__ right_child,
    const float* __restrict__ dembed, const float* __restrict__ sembed,
    const float* __restrict__ node_in, float* __restrict__ node_out,
    int nodeA, int nodeB)
{
  const int N = 1024;
  __shared__ float As[BK][BM + 2];   // padded, stride 34
  __shared__ float Ws[BK][BN];

  const int tid = threadIdx.x;
  const int n0 = blockIdx.x * BN;
  const int m0 = blockIdx.y * BM;

  const int am = tid >> 3;            // 0..31   A tile row (this thread stages)
  const int ak = (tid & 7) * 4;       // 0..28   A tile k
  const int wk = tid >> 3;            // 0..31   W tile k
  const int wn = (tid & 7) * 8;       // 0..56   W tile n
  const int rm = (tid >> 4) * 2;      // compute rows
  const int cn = (tid & 15) * 4;      // compute cols

  // Per-thread A addressing setup (hoisted out of the K-loop)
  float ainv = 1.0f;
  int lcn = 0, rcn = 0, arow_b = 0;
  if (AMODE == 1) {
    int m = m0 + am; int b = m >> 2; int s = m & 3;
    int bs = boundaries[b * 4 + s];
    int bn = (s < 3) ? boundaries[b * 4 + s + 1] : lengths[b];
    ainv = 1.0f / fmaxf((float)(bn - bs), 1.0f);
  } else if (AMODE == 2) {
    int mrow = m0 + am; int mi = mrow >> 6; int b = mrow & 63;
    int node = mi ? nodeB : nodeA;
    lcn = left_child[node]; rcn = right_child[node];
    arow_b = b;
  }

  float acc[2][4] = {{0.f,0.f,0.f,0.f},{0.f,0.f,0.f,0.f}};

  // ---- prefetch tile 0 into registers ----
  float4 av, wv0, wv1;
  {
    if (AMODE == 2) {
      int col = ak;
      int child = (col < 1024) ? lcn : rcn;
      av = *(const float4*)(node_in + (size_t)(arow_b * NNODE + child) * 1024 + (col & 1023));
    } else {
      av = *(const float4*)(A + (size_t)(m0 + am) * K + ak);
    }
    wv0 = *(const float4*)(W + (size_t)wk * N + n0 + wn);
    wv1 = *(const float4*)(W + (size_t)wk * N + n0 + wn + 4);
  }

  for (int k0 = 0; k0 < K; k0 += BK) {
    __syncthreads();                  // readers of previous tile done
    As[ak + 0][am] = av.x * ainv;
    As[ak + 1][am] = av.y * ainv;
    As[ak + 2][am] = av.z * ainv;
    As[ak + 3][am] = av.w * ainv;
    *(float4*)&Ws[wk][wn]     = wv0;
    *(float4*)&Ws[wk][wn + 4] = wv1;
    __syncthreads();                  // staging visible

    // issue next tile's loads NOW; waited at next iteration's store
    const int kn = k0 + BK;
    if (kn < K) {
      if (AMODE == 2) {
        int col = kn + ak;
        int child = (col < 1024) ? lcn : rcn;
        av = *(const float4*)(node_in + (size_t)(arow_b * NNODE + child) * 1024 + (col & 1023));
      } else {
        av = *(const float4*)(A + (size_t)(m0 + am) * K + kn + ak);
      }
      wv0 = *(const float4*)(W + (size_t)(kn + wk) * N + n0 + wn);
      wv1 = *(const float4*)(W + (size_t)(kn + wk) * N + n0 + wn + 4);
    }

    #pragma unroll
    for (int kk = 0; kk < BK; ++kk) {
      float2 a2 = *(const float2*)&As[kk][rm];
      float4 w  = *(const float4*)&Ws[kk][cn];
      acc[0][0] += a2.x * w.x; acc[0][1] += a2.x * w.y;
      acc[0][2] += a2.x * w.z; acc[0][3] += a2.x * w.w;
      acc[1][0] += a2.y * w.x; acc[1][1] += a2.y * w.y;
      acc[1][2] += a2.y * w.z; acc[1][3] += a2.y * w.w;
    }
  }

  // ---- epilogue ----
  #pragma unroll
  for (int r = 0; r < 2; ++r) {
    const int m = m0 + rm + r;
    const int n = n0 + cn;
    float4 x;
    x.x = acc[r][0] + bias[n + 0];
    x.y = acc[r][1] + bias[n + 1];
    x.z = acc[r][2] + bias[n + 2];
    x.w = acc[r][3] + bias[n + 3];

    if (EPI == 0) {
      x.x = gelu_f(x.x); x.y = gelu_f(x.y); x.z = gelu_f(x.z); x.w = gelu_f(x.w);
      *(float4*)(C + (size_t)m * N + n) = x;
    } else if (EPI == 1) {
      int b = m >> 2; int s = m & 3;
      int node  = leaf_order[b * 4 + s];
      int nclip = node < 0 ? 0 : node;
      int bs = boundaries[b * 4 + s];
      int bn = (s < 3) ? boundaries[b * 4 + s + 1] : lengths[b];
      bool ok = (node >= 0) && (is_leaf[b * NNODE + nclip] != 0) && (bn - bs > 0);
      int d = depth[nclip];
      const float* de = dembed + (size_t)d * 1024 + n;
      float sc = ok ? 1.0f : 0.0f;
      x.x = (x.x + de[0]) * sc; x.y = (x.y + de[1]) * sc;
      x.z = (x.z + de[2]) * sc; x.w = (x.w + de[3]) * sc;
      *(float4*)(node_out + (size_t)(b * NNODE + nclip) * 1024 + n) = x;
    } else if (EPI == 2) {
      int mi = m >> 6; int b = m & 63;
      int node = mi ? nodeB : nodeA;
      bool ii = (active[b * NNODE + node] != 0) && (is_leaf[b * NNODE + node] == 0);
      int d = depth[node];
      const float* de = dembed + (size_t)d * 1024 + n;
      float sc = ii ? 1.0f : 0.0f;
      x.x = (x.x + de[0]) * sc; x.y = (x.y + de[1]) * sc;
      x.z = (x.z + de[2]) * sc; x.w = (x.w + de[3]) * sc;
      *(float4*)(node_out + (size_t)(b * NNODE + node) * 1024 + n) = x;
    } else { // EPI == 3: root merge (node 0) + topology hash + shape_embed -> out
      int b = m & 63;
      bool ii = (active[b * NNODE + 0] != 0) && (is_leaf[b * NNODE + 0] == 0);
      int d = depth[0];
      const float* de = dembed + (size_t)d * 1024 + n;
      float sc = ii ? 1.0f : 0.0f;
      long long h = 0, w = 1;
      #pragma unroll
      for (int i = 0; i < NNODE; ++i) {
        long long p = (long long)active[b * NNODE + i] * 2
                    + (long long)is_leaf[b * NNODE + i];
        h += p * w;
        w *= 31;
      }
      long long a = h < 0 ? -h : h;
      int sid = (int)(a % 256);
      const float* se = sembed + (size_t)sid * 1024 + n;
      x.x = (x.x + de[0]) * sc + se[0];
      x.y = (x.y + de[1]) * sc + se[1];
      x.z = (x.z + de[2]) * sc + se[2];
      x.w = (x.w + de[3]) * sc + se[3];
      *(float4*)(node_out + (size_t)b * 1024 + n) = x;
    }
  }
}

// ---------------------------------------------------------------------------
extern "C" void kernel_launch(void* const* d_in, const int* in_sizes, int n_in,
                              void* d_out, int out_size, void* d_ws, size_t ws_size,
                              hipStream_t stream)
{
  const float* states     = (const float*)d_in[0];
  // d_in[1] (mask) is redundant: mask[b][t] == (t < lengths[b])
  const int* lengths      = (const int*)d_in[2];
  const int* boundaries   = (const int*)d_in[3];
  const int* leaf_order   = (const int*)d_in[4];
  const int* active       = (const int*)d_in[5];
  const int* is_leaf      = (const int*)d_in[6];
  const int* left_child   = (const int*)d_in[7];
  const int* right_child  = (const int*)d_in[8];
  const int* depth        = (const int*)d_in[9];
  const float* W1  = (const float*)d_in[10];
  const float* b1  = (const float*)d_in[11];
  const float* W2  = (const float*)d_in[12];
  const float* b2  = (const float*)d_in[13];
  const float* Wm1 = (const float*)d_in[14];
  const float* bm1 = (const float*)d_in[15];
  const float* Wm2 = (const float*)d_in[16];
  const float* bm2 = (const float*)d_in[17];
  const float* dembed = (const float*)d_in[18];
  const float* sembed = (const float*)d_in[19];
  float* out = (float*)d_out;

  // workspace layout (floats)
  float* pooled    = (float*)d_ws;              // 256*1024 (zero-init)
  float* H1        = pooled + 256 * 1024;       // 256*1024
  float* Hm        = H1 + 256 * 1024;           // 128*1024
  float* node_repr = Hm + 128 * 1024;           // 448*1024

  hipMemsetAsync(pooled, 0, (size_t)256 * 1024 * sizeof(float), stream);

  // 1) pooling partial sums
  pool_kernel<<<dim3(SEQ / TCHUNK, NBAT), 256, 0, stream>>>(
      states, boundaries, lengths, pooled);

  // 2) H1 = gelu(pooled/cnt @ W1 + b1)            M=256 K=1024
  gemm_kernel<1, 0><<<dim3(16, 8), 256, 0, stream>>>(
      pooled, W1, b1, H1, 256, 1024,
      boundaries, lengths, leaf_order, active, is_leaf, depth,
      left_child, right_child, dembed, sembed, nullptr, nullptr, -1, -1);

  // 3) leaves: node_repr[leaf] = (H1 @ W2 + b2 + dembed) * leaf_ok   M=256 K=1024
  gemm_kernel<0, 1><<<dim3(16, 8), 256, 0, stream>>>(
      H1, W2, b2, nullptr, 256, 1024,
      boundaries, lengths, leaf_order, active, is_leaf, depth,
      left_child, right_child, dembed, sembed, nullptr, node_repr, -1, -1);

  // 4) level-1 merges (nodes 1 and 2, independent):  M=128 K=2048
  gemm_kernel<2, 0><<<dim3(16, 4), 256, 0, stream>>>(
      nullptr, Wm1, bm1, Hm, 128, 2048,
      boundaries, lengths, leaf_order, active, is_leaf, depth,
      left_child, right_child, dembed, sembed, node_repr, nullptr, 1, 2);
  gemm_kernel<0, 2><<<dim3(16, 4), 256, 0, stream>>>(
      Hm, Wm2, bm2, nullptr, 128, 1024,
      boundaries, lengths, leaf_order, active, is_leaf, depth,
      left_child, right_child, dembed, sembed, nullptr, node_repr, 1, 2);

  // 5) root merge (node 0):  M=64 K=2048, then fused hash+shape_embed -> out
  gemm_kernel<2, 0><<<dim3(16, 2), 256, 0, stream>>>(
      nullptr, Wm1, bm1, Hm, 64, 2048,
      boundaries, lengths, leaf_order, active, is_leaf, depth,
      left_child, right_child, dembed, sembed, node_repr, nullptr, 0, 0);
  gemm_kernel<0, 3><<<dim3(16, 2), 256, 0, stream>>>(
      Hm, Wm2, bm2, nullptr, 64, 1024,
      boundaries, lengths, leaf_order, active, is_leaf, depth,
      left_child, right_child, dembed, sembed, nullptr, out, 0, 0);
}